// Round 5
// baseline (654.937 us; speedup 1.0000x reference)
//
#include <hip/hip_runtime.h>

// SoftCLDiceLoss fully fused, round 5: packed-f16 morphology, asm-forced
// v_pk ops, vertical-first separable 3x3 passes, SD=50 (conflict-spread:
// erode strip shift 12, dilate strip shift 8 mod 32), no per-iter masking
// (epilogue rc-bounds discard invalid halves), skel state stored negated
// so the update is fma/add/xor only. 2 syncs/iter, 4 blocks/CU.

#define TILE 64
#define HALO 12
#define RROWS 92
#define SD 50                    // row stride in dwords (100 halves)
#define IMG 1024
#define NBC 16
#define NITER 11
#define LEPS 1e-6f

typedef unsigned int u32;

struct __align__(16) U4 { u32 v[4]; };

__device__ __forceinline__ u32 pk_min(u32 a, u32 b) {
    u32 d; asm("v_pk_min_f16 %0, %1, %2" : "=v"(d) : "v"(a), "v"(b)); return d;
}
__device__ __forceinline__ u32 pk_max(u32 a, u32 b) {
    u32 d; asm("v_pk_max_f16 %0, %1, %2" : "=v"(d) : "v"(a), "v"(b)); return d;
}
__device__ __forceinline__ u32 pk_max0(u32 a) {
    u32 d; asm("v_pk_max_f16 %0, %1, 0" : "=v"(d) : "v"(a)); return d;
}
__device__ __forceinline__ u32 pk_add(u32 a, u32 b) {
    u32 d; asm("v_pk_add_f16 %0, %1, %2" : "=v"(d) : "v"(a), "v"(b)); return d;
}
__device__ __forceinline__ u32 pk_fma(u32 a, u32 b, u32 c) {
    u32 d; asm("v_pk_fma_f16 %0, %1, %2, %3" : "=v"(d) : "v"(a), "v"(b), "v"(c)); return d;
}
__device__ __forceinline__ u32 dpp_prev16(u32 x) {   // lane i <- i-1 within 16-lane row, 0-fill
    return (u32)__builtin_amdgcn_update_dpp(0, (int)x, 0x101, 0xf, 0xf, true);
}
__device__ __forceinline__ u32 dpp_next16(u32 x) {   // lane i <- i+1 within 16-lane row, 0-fill
    return (u32)__builtin_amdgcn_update_dpp(0, (int)x, 0x111, 0xf, 0xf, true);
}
__device__ __forceinline__ u32 alignh(u32 hi, u32 lo) {   // ((hi<<32)|lo)>>16
    return __builtin_amdgcn_alignbit(hi, lo, 16);
}
__device__ __forceinline__ float sigmoidf(float x) { return 1.0f / (1.0f + __expf(-x)); }

// 3-wide horizontal min/max over 8 packed halves; neighbors via DPP.
template<bool IS_MIN>
__device__ __forceinline__ void hpass(const u32 d[4], u32 o[4]) {
    u32 dm = dpp_prev16(d[3]);
    u32 dp = dpp_next16(d[0]);
    u32 a[5];
    a[0] = alignh(d[0], dm);
    a[1] = alignh(d[1], d[0]);
    a[2] = alignh(d[2], d[1]);
    a[3] = alignh(d[3], d[2]);
    a[4] = alignh(dp,   d[3]);
#pragma unroll
    for (int q = 0; q < 4; ++q) {
        if (IS_MIN) o[q] = pk_min(pk_min(a[q], d[q]), a[q + 1]);
        else        o[q] = pk_max(pk_max(a[q], d[q]), a[q + 1]);
    }
}

__global__ __launch_bounds__(256, 4)
void skel_tile_kernel(const float* __restrict__ pred,
                      const float* __restrict__ target,
                      float* __restrict__ ws)
{
    __shared__ __align__(16) u32 bufA[RROWS * SD];
    __shared__ __align__(16) u32 bufB[RROWS * SD];

    const int tid = threadIdx.x;
    const int bc  = blockIdx.z & (NBC - 1);
    const int img = blockIdx.z >> 4;
    const int r0  = blockIdx.y * TILE;
    const int c0  = blockIdx.x * TILE;

    const float* src = (img == 0) ? pred : target;
    const size_t base = (size_t)bc * (size_t)(IMG * IMG);

    const bool edgeT = (blockIdx.y == 0);
    const bool edgeB = (blockIdx.y == 15);
    const bool edgeL = (blockIdx.x == 0);
    const bool edgeR = (blockIdx.x == 15);
    const int rdLo = edgeT ? 12 : 0;
    const int rdHi = edgeB ? 75 : (RROWS - 1);

    // ---- load region rows 0..87, cols 0..95 (halves), replicate-clamped ----
    for (int t = tid; t < 88 * 12; t += 256) {
        int rr = t / 12;
        int g  = t - rr * 12;
        int gr = min(max(r0 + rr - HALO, 0), IMG - 1);
        const float* rowp = src + base + (size_t)gr * IMG;
        float f[8];
        int gc0 = c0 + 8 * g - HALO;
        if (g <= 10 && gc0 >= 0 && gc0 + 8 <= IMG) {
            float4 v0 = *(const float4*)(rowp + gc0);
            float4 v1 = *(const float4*)(rowp + gc0 + 4);
            f[0] = v0.x; f[1] = v0.y; f[2] = v0.z; f[3] = v0.w;
            f[4] = v1.x; f[5] = v1.y; f[6] = v1.z; f[7] = v1.w;
        } else {
#pragma unroll
            for (int i = 0; i < 8; ++i) {
                int rc = min(8 * g + i, 87);
                int gc = min(max(c0 + rc - HALO, 0), IMG - 1);
                f[i] = rowp[gc];
            }
        }
        U4 u;
#pragma unroll
        for (int q = 0; q < 4; ++q) {
            float a = f[2 * q], b = f[2 * q + 1];
            if (img == 0) { a = sigmoidf(a); b = sigmoidf(b); }
            else { a = fminf(fmaxf(a, 0.f), 1.f); b = fminf(fmaxf(b, 0.f), 1.f); }
            _Float16 ha = (_Float16)a, hb = (_Float16)b;
            u32 ua, ub;
            __builtin_memcpy(&ua, &ha, 2);
            __builtin_memcpy(&ub, &hb, 2);
            u.v[q] = (ua & 0xFFFFu) | (ub << 16);
        }
        *(uint4*)&bufA[rr * SD + 4 * g] = *(const uint4*)u.v;
    }

    // ---- strip / lane geometry ----
    const int strip = tid >> 4;                 // 0..15
    const int g16   = tid & 15;                 // lane within 16-lane DPP row
    const int coldw = 4 * min(g16, 11);         // clamped dword col (16B aligned)
    const bool wact = (g16 < 12);

    const int rs_e = min(1 + 6 * strip, 85);    // erode out rows rs_e..rs_e+5 (mask <=86)
    const int rs_d = 12 + 4 * strip;            // dilate out rows rs_d..rs_d+3 (12..75)

    u32 nS[4][4];                               // negated skel: nS = -S
#pragma unroll
    for (int j = 0; j < 4; ++j)
#pragma unroll
        for (int q = 0; q < 4; ++q) nS[j][q] = 0u;

    u32* cur = bufA;
    u32* oth = bufB;

    __syncthreads();

    for (int k = 0; k < NITER; ++k) {
        // ---- erode 3x3 (min): cur -> oth; vertical-first; no row clamps ----
        {
            U4 w[8];
            const u32* p = cur + (rs_e - 1) * SD + coldw;
#pragma unroll
            for (int j = 0; j < 8; ++j)
                *(uint4*)w[j].v = *(const uint4*)(p + j * SD);
            u32* q = oth + rs_e * SD + coldw;
#pragma unroll
            for (int j = 0; j < 6; ++j) {
                u32 v[4], o[4];
#pragma unroll
                for (int qd = 0; qd < 4; ++qd)
                    v[qd] = pk_min(pk_min(w[j].v[qd], w[j + 1].v[qd]), w[j + 2].v[qd]);
                hpass<true>(v, o);
                int row = rs_e + j;
                if (wact && row <= 86)
                    *(uint4*)(q + j * SD) = *(const uint4*)o;
            }
        }
        __syncthreads();

        // ---- dilate 3x3 (max) on oth, vertical-first, + delta + skel ----
        {
            U4 w[6];
            if (!(edgeT || edgeB)) {
                const u32* p = oth + (rs_d - 1) * SD + coldw;
#pragma unroll
                for (int j = 0; j < 6; ++j)
                    *(uint4*)w[j].v = *(const uint4*)(p + j * SD);
            } else {
#pragma unroll
                for (int j = 0; j < 6; ++j) {
                    int rr = min(max(rs_d - 1 + j, rdLo), rdHi);
                    *(uint4*)w[j].v = *(const uint4*)(oth + rr * SD + coldw);
                }
            }

            const u32* pc = cur + rs_d * SD + coldw;
#pragma unroll
            for (int j = 0; j < 4; ++j) {
                u32 v[4], m[4];
#pragma unroll
                for (int qd = 0; qd < 4; ++qd)
                    v[qd] = pk_max(pk_max(w[j].v[qd], w[j + 1].v[qd]), w[j + 2].v[qd]);
                hpass<false>(v, m);

                // image-edge column repair (replicate), 2/16 blocks
                if (edgeL && g16 == 1) {     // out col12.lo := max(v12, v13)
                    u32 pm = pk_max(v[2], alignh(v[2], v[2]));
                    m[2] = (m[2] & 0xFFFF0000u) | (pm & 0xFFFFu);
                }
                if (edgeR && g16 == 9) {     // out col75.hi := max(v74, v75)
                    u32 pm = pk_max(v[1], alignh(v[1], v[1]));
                    m[1] = (m[1] & 0x0000FFFFu) | (pm & 0xFFFF0000u);
                }

                U4 a; *(uint4*)a.v = *(const uint4*)(pc + j * SD);
#pragma unroll
                for (int qd = 0; qd < 4; ++qd) {
                    u32 d = pk_max0(pk_add(a.v[qd], m[qd] ^ 0x80008000u));  // relu(e_k - D)
                    u32 t = pk_max0(pk_fma(nS[j][qd], d, d));               // relu(d - S*d)
                    nS[j][qd] = pk_add(nS[j][qd], t ^ 0x80008000u);         // nS -= t
                }
            }
        }

        { u32* t_ = cur; cur = oth; oth = t_; }
        __syncthreads();
    }

    // ---- tile sums: sum(skel), sum(skel * other) ----
    const float* osrc = (img == 0) ? target : pred;
    float s_sum = 0.0f, sp_sum = 0.0f;
#pragma unroll
    for (int j = 0; j < 4; ++j) {
        int orow = r0 + 4 * strip + j;
#pragma unroll
        for (int qd = 0; qd < 4; ++qd) {
#pragma unroll
            for (int e = 0; e < 2; ++e) {
                int rc = 8 * g16 + 2 * qd + e;
                if (rc >= 12 && rc <= 75) {
                    unsigned short hu = (unsigned short)(nS[j][qd] >> (16 * e));
                    _Float16 hv;
                    __builtin_memcpy(&hv, &hu, 2);
                    float sv = -(float)hv;
                    float ov = osrc[base + (size_t)orow * IMG + (c0 + rc - HALO)];
                    if (img == 1) ov = sigmoidf(ov);
                    s_sum  += sv;
                    sp_sum += sv * ov;
                }
            }
        }
    }

#pragma unroll
    for (int off = 32; off > 0; off >>= 1) {
        s_sum  += __shfl_down(s_sum,  off, 64);
        sp_sum += __shfl_down(sp_sum, off, 64);
    }
    float* red = (float*)bufA;
    if ((tid & 63) == 0) {
        red[(tid >> 6) * 2 + 0] = sp_sum;
        red[(tid >> 6) * 2 + 1] = s_sum;
    }
    __syncthreads();
    if (tid == 0) {
        float a = (red[0] + red[2]) + (red[4] + red[6]);
        float b = (red[1] + red[3]) + (red[5] + red[7]);
        float* acc = ws + (size_t)blockIdx.z * 2;
        atomicAdd(acc + 0, a);   // sum skel * other
        atomicAdd(acc + 1, b);   // sum skel
    }
}

__global__ void finalize_kernel(const float* __restrict__ ws, float* __restrict__ out)
{
    if (threadIdx.x == 0) {
        float acc = 0.0f;
        for (int bc = 0; bc < NBC; ++bc) {
            float spt = ws[(0 * NBC + bc) * 2 + 0];
            float sp  = ws[(0 * NBC + bc) * 2 + 1];
            float stp = ws[(1 * NBC + bc) * 2 + 0];
            float st  = ws[(1 * NBC + bc) * 2 + 1];
            float tprec = spt / (sp + LEPS);
            float tsens = stp / (st + LEPS);
            acc += 1.0f - 2.0f * tprec * tsens / (tprec + tsens + LEPS);
        }
        out[0] = acc / (float)NBC;
    }
}

extern "C" void kernel_launch(void* const* d_in, const int* in_sizes, int n_in,
                              void* d_out, int out_size, void* d_ws, size_t ws_size,
                              hipStream_t stream) {
    const float* pred   = (const float*)d_in[0];
    const float* target = (const float*)d_in[1];
    float* ws  = (float*)d_ws;
    float* out = (float*)d_out;

    hipMemsetAsync(d_ws, 0, 2 * NBC * 2 * sizeof(float), stream);

    dim3 grid(IMG / TILE, IMG / TILE, 2 * NBC);   // 16 x 16 x 32
    skel_tile_kernel<<<grid, 256, 0, stream>>>(pred, target, ws);
    finalize_kernel<<<1, 64, 0, stream>>>(ws, out);
}

// Round 6
// 594.343 us; speedup vs baseline: 1.1020x; 1.1020x over previous
//
#include <hip/hip_runtime.h>

// SoftCLDiceLoss fully fused, round 6: wave-autonomous register-resident
// morphology. Each wave owns 104 cols x 16 rows of output; the 40-row
// (halo-12) packed-f16 region lives in two register planes (A/B ping-pong,
// pair-unrolled loop). Horizontal neighbors via full-wave DPP shl/shr +
// v_alignbit; vertical = static register indexing. NO LDS, NO barriers.
// Erosion edges rely on min-safety of replicated/stale halo (stale >= true
// erosion); dilation gets exact replicate patches on edge bands only.

#define IMG 1024
#define NBC 16
#define LEPS 1e-6f

typedef unsigned int u32;

__device__ __forceinline__ u32 pk_min(u32 a, u32 b) {
    u32 d; asm("v_pk_min_f16 %0, %1, %2" : "=v"(d) : "v"(a), "v"(b)); return d;
}
__device__ __forceinline__ u32 pk_max(u32 a, u32 b) {
    u32 d; asm("v_pk_max_f16 %0, %1, %2" : "=v"(d) : "v"(a), "v"(b)); return d;
}
__device__ __forceinline__ u32 pk_max0(u32 a) {
    u32 d; asm("v_pk_max_f16 %0, %1, 0" : "=v"(d) : "v"(a)); return d;
}
__device__ __forceinline__ u32 pk_add(u32 a, u32 b) {
    u32 d; asm("v_pk_add_f16 %0, %1, %2" : "=v"(d) : "v"(a), "v"(b)); return d;
}
__device__ __forceinline__ u32 pk_fma(u32 a, u32 b, u32 c) {
    u32 d; asm("v_pk_fma_f16 %0, %1, %2, %3" : "=v"(d) : "v"(a), "v"(b), "v"(c)); return d;
}
__device__ __forceinline__ u32 dpp_prev(u32 x) {   // lane i <- i-1 (wave_shl1), 0-fill
    return (u32)__builtin_amdgcn_update_dpp(0, (int)x, 0x130, 0xf, 0xf, true);
}
__device__ __forceinline__ u32 dpp_next(u32 x) {   // lane i <- i+1 (wave_shr1), 0-fill
    return (u32)__builtin_amdgcn_update_dpp(0, (int)x, 0x138, 0xf, 0xf, true);
}
__device__ __forceinline__ u32 alignh(u32 hi, u32 lo) {   // (lo.hi16 | hi.lo16<<16)
    return __builtin_amdgcn_alignbit(hi, lo, 16);
}
__device__ __forceinline__ u32 swap16(u32 x) { return alignh(x, x); }
__device__ __forceinline__ float sigmoidf(float x) { return 1.0f / (1.0f + __expf(-x)); }

// One soft-skel iteration: erode SRC->DST (rows 1..38), then dilate DST rows
// 12..27, delta vs SRC, skel update. All row indices static after unroll.
#define STEP(SRC, DST)                                                          \
    {                                                                           \
        u32 pv = SRC[0];                                                        \
        _Pragma("unroll")                                                       \
        for (int r = 1; r <= 38; ++r) {                                         \
            u32 v = pk_min(pk_min(pv, SRC[r]), SRC[r + 1]);                     \
            pv = SRC[r];                                                        \
            u32 dm = dpp_prev(v);                                               \
            u32 dp = dpp_next(v);                                               \
            DST[r] = pk_min(pk_min(alignh(v, dm), v), alignh(dp, v));           \
        }                                                                       \
        _Pragma("unroll")                                                       \
        for (int r = 12; r <= 27; ++r) {                                        \
            u32 up = (r == 12) ? (edgeT ? DST[12] : DST[11]) : DST[r - 1];      \
            u32 dn = (r == 27) ? (edgeB ? DST[27] : DST[28]) : DST[r + 1];      \
            u32 v = pk_max(pk_max(up, DST[r]), dn);                             \
            u32 dm = dpp_prev(v);                                               \
            u32 dp = dpp_next(v);                                               \
            u32 m = pk_max(pk_max(alignh(v, dm), v), alignh(dp, v));            \
            if (edgeL) {   /* out col12.lo := max(v12,v13), lane 6 */           \
                u32 pm = pk_max(v, swap16(v));                                  \
                if (lane == 6) m = (m & 0xFFFF0000u) | (pm & 0xFFFFu);          \
            }                                                                   \
            if (edgeR) {   /* out col1023 (w=99).hi := max(v98,v99), lane 49 */ \
                u32 pm = pk_max(v, swap16(v));                                  \
                if (lane == 49) m = (m & 0x0000FFFFu) | (pm & 0xFFFF0000u);     \
            }                                                                   \
            u32 d = pk_max0(pk_add(SRC[r], m ^ 0x80008000u));                   \
            u32 t = pk_max0(pk_fma(nS[r - 12], d, d));                          \
            nS[r - 12] = pk_add(nS[r - 12], t ^ 0x80008000u);                   \
        }                                                                       \
    }

__global__ __launch_bounds__(256, 3)
void skel_wave_kernel(const float* __restrict__ pred,
                      const float* __restrict__ target,
                      float* __restrict__ ws)
{
    const int tid    = threadIdx.x;
    const int lane   = tid & 63;
    const int waveId = tid >> 6;

    const int bc  = blockIdx.z & (NBC - 1);
    const int img = blockIdx.z >> 4;
    const int tr0 = (blockIdx.y * 4 + waveId) * 16;   // tile row base (0..1008)
    const int cb0 = blockIdx.x * 104;                 // data col base
    const int wc0 = cb0 - 12;                         // window col 0 -> image col

    const float* src = (img == 0) ? pred : target;
    const size_t base = (size_t)bc * (size_t)(IMG * IMG);

    const bool edgeT = (tr0 == 0);
    const bool edgeB = (tr0 == IMG - 16);
    const bool edgeL = (blockIdx.x == 0);
    const bool edgeR = (blockIdx.x == 9);

    const int ic0 = wc0 + 2 * lane;                   // image col of lo half

    // ---- load 40-row region into plane A (f16x2 per lane-row) ----
    u32 A[40], B[40];
#pragma unroll
    for (int i = 0; i < 40; ++i) {
        int ir = min(max(tr0 - 12 + i, 0), IMG - 1);
        const float* rowp = src + base + (size_t)ir * IMG;
        float a, b;
        if (!(edgeL || edgeR)) {
            float2 f2 = *(const float2*)(rowp + ic0);
            a = f2.x; b = f2.y;
        } else {
            a = rowp[min(max(ic0, 0), IMG - 1)];
            b = rowp[min(max(ic0 + 1, 0), IMG - 1)];
        }
        if (img == 0) { a = sigmoidf(a); b = sigmoidf(b); }
        else { a = fminf(fmaxf(a, 0.f), 1.f); b = fminf(fmaxf(b, 0.f), 1.f); }
        _Float16 ha = (_Float16)a, hb = (_Float16)b;
        unsigned short ua, ub;
        __builtin_memcpy(&ua, &ha, 2);
        __builtin_memcpy(&ub, &hb, 2);
        A[i] = (u32)ua | ((u32)ub << 16);
    }
    B[0] = A[0];
    B[39] = A[39];

    u32 nS[16];                                       // negated skel: nS = -S
#pragma unroll
    for (int j = 0; j < 16; ++j) nS[j] = 0u;

    // ---- 11 iterations: 1 x (A->B) + 5 x (B->A, A->B) ----
    STEP(A, B)
#pragma unroll 1
    for (int p = 0; p < 5; ++p) {
        STEP(B, A)
        STEP(A, B)
    }

    // ---- per-lane column validity (window col in [12,115], image col <1024) ----
    const int wlo = 2 * lane, whi = 2 * lane + 1;
    const float mLo = (wlo >= 12 && wlo <= 115 && ic0 <= IMG - 1) ? 1.f : 0.f;
    const float mHi = (whi >= 12 && whi <= 115 && ic0 + 1 <= IMG - 1) ? 1.f : 0.f;

    // ---- sums: sum(skel), sum(skel * other) over tile rows ----
    const float* osrc = (img == 0) ? target : pred;
    float s_sum = 0.f, sp_sum = 0.f;
#pragma unroll
    for (int j = 0; j < 16; ++j) {
        int ir = tr0 + j;
        const float* rowp = osrc + base + (size_t)ir * IMG;
        float oa, ob;
        if (!(edgeL || edgeR)) {
            float2 f2 = *(const float2*)(rowp + ic0);
            oa = f2.x; ob = f2.y;
        } else {
            oa = rowp[min(max(ic0, 0), IMG - 1)];
            ob = rowp[min(max(ic0 + 1, 0), IMG - 1)];
        }
        if (img == 1) { oa = sigmoidf(oa); ob = sigmoidf(ob); }
        unsigned short ul = (unsigned short)(nS[j] & 0xFFFFu);
        unsigned short uh = (unsigned short)(nS[j] >> 16);
        _Float16 hl, hh;
        __builtin_memcpy(&hl, &ul, 2);
        __builtin_memcpy(&hh, &uh, 2);
        float svLo = -(float)hl * mLo;
        float svHi = -(float)hh * mHi;
        s_sum  += svLo + svHi;
        sp_sum += svLo * oa + svHi * ob;
    }

#pragma unroll
    for (int off = 32; off > 0; off >>= 1) {
        s_sum  += __shfl_down(s_sum,  off, 64);
        sp_sum += __shfl_down(sp_sum, off, 64);
    }
    if (lane == 0) {
        float* acc = ws + (size_t)blockIdx.z * 2;
        atomicAdd(acc + 0, sp_sum);   // sum skel * other
        atomicAdd(acc + 1, s_sum);    // sum skel
    }
}

__global__ void finalize_kernel(const float* __restrict__ ws, float* __restrict__ out)
{
    if (threadIdx.x == 0) {
        float acc = 0.0f;
        for (int bc = 0; bc < NBC; ++bc) {
            float spt = ws[(0 * NBC + bc) * 2 + 0];
            float sp  = ws[(0 * NBC + bc) * 2 + 1];
            float stp = ws[(1 * NBC + bc) * 2 + 0];
            float st  = ws[(1 * NBC + bc) * 2 + 1];
            float tprec = spt / (sp + LEPS);
            float tsens = stp / (st + LEPS);
            acc += 1.0f - 2.0f * tprec * tsens / (tprec + tsens + LEPS);
        }
        out[0] = acc / (float)NBC;
    }
}

extern "C" void kernel_launch(void* const* d_in, const int* in_sizes, int n_in,
                              void* d_out, int out_size, void* d_ws, size_t ws_size,
                              hipStream_t stream) {
    const float* pred   = (const float*)d_in[0];
    const float* target = (const float*)d_in[1];
    float* ws  = (float*)d_ws;
    float* out = (float*)d_out;

    hipMemsetAsync(d_ws, 0, 2 * NBC * 2 * sizeof(float), stream);

    dim3 grid(10, 16, 2 * NBC);   // 10 col-bands x (16 blocks x 4 waves = 64 row-bands) x 32 images
    skel_wave_kernel<<<grid, 256, 0, stream>>>(pred, target, ws);
    finalize_kernel<<<1, 64, 0, stream>>>(ws, out);
}